// Round 12
// baseline (147.457 us; speedup 1.0000x reference)
//
#include <hip/hip_runtime.h>
#include <hip/hip_bf16.h>
#include <stdint.h>

#define B_ 16
#define N_ 4096
#define E_ 65536
#define C_ 128   // CIN == COUT
#define ECAP 81920  // padded edge capacity per batch (E + 3*N = 77824 max)

typedef unsigned short u16;
typedef unsigned int u32;
typedef unsigned char u8;
using f32x4 = __attribute__((ext_vector_type(4))) float;
using f32x2 = __attribute__((ext_vector_type(2))) float;
using s16x8 = __attribute__((ext_vector_type(8))) short;

__device__ __forceinline__ u16 f2bf(float f) {
  u32 u = __builtin_bit_cast(u32, f);
  u = (u + 0x7FFFu + ((u >> 16) & 1u)) >> 16;
  return (u16)u;
}
__device__ __forceinline__ float bflo(u32 u) {   // low bf16 -> f32
  return __builtin_bit_cast(float, u << 16);
}
__device__ __forceinline__ float bfhi(u32 u) {   // high bf16 -> f32
  return __builtin_bit_cast(float, u & 0xFFFF0000u);
}

// ---- prep: fused xconv (blocks 0..4095) + wfrag (4096..4351) + hist (4352..4607)
// wfrag bakes the Chebyshev recombination:
//   out = x(W0-W2) + g1(W1-3W3) + g2(2W2) + g3(4W3),  g_k = L^k x

__global__ __launch_bounds__(256) void prep_kernel(const float* __restrict__ x,
                                                   u16* __restrict__ xb,
                                                   const float* __restrict__ w,
                                                   u16* __restrict__ wf,
                                                   const int* __restrict__ rows,
                                                   int* __restrict__ hist) {
  int blk = blockIdx.x;
  int t = threadIdx.x;
  if (blk < 4096) {
    // x -> bf16, XCD-pinned
    int xcd = blk & 7;
    int j   = blk >> 3;              // 0..511
    int b   = xcd * 2 + (j >> 8);
    size_t base = (size_t)b * N_ * C_ + ((j & 255) * 256 + t) * 8;
    const float4* xp = reinterpret_cast<const float4*>(x + base);
    float4 a0 = xp[0];
    float4 a1 = xp[1];
    uint4 p;
    p.x = (u32)f2bf(a0.x) | ((u32)f2bf(a0.y) << 16);
    p.y = (u32)f2bf(a0.z) | ((u32)f2bf(a0.w) << 16);
    p.z = (u32)f2bf(a1.x) | ((u32)f2bf(a1.y) << 16);
    p.w = (u32)f2bf(a1.z) | ((u32)f2bf(a1.w) << 16);
    *reinterpret_cast<uint4*>(xb + base) = p;
  } else if (blk < 4352) {
    // W fragment pack with recombined weights, MFMA B-operand order
    int tid = (blk - 4096) * 256 + t;   // 0..65535
    int j  = tid & 7;
    int l  = (tid >> 3) & 63;
    int ct = (tid >> 9) & 7;
    int ks = tid >> 12;
    int g  = l >> 4;
    int k  = ks * 32 + g * 8 + j;       // 0..511
    int kk = k >> 7;
    int i  = k & 127;
    int o  = ct * 16 + (l & 15);
    float a = w[(kk * C_ + i) * C_ + o];
    float r;
    if (kk == 0)      r = a - w[(2 * C_ + i) * C_ + o];
    else if (kk == 1) r = a - 3.f * w[(3 * C_ + i) * C_ + o];
    else if (kk == 2) r = 2.f * a;
    else              r = 4.f * a;
    wf[tid] = f2bf(r);
  } else {
    // per-(batch,chunk) LDS histogram of rows
    __shared__ int h[N_];
    int hblk = blk - 4352;              // 0..255
    int b = hblk >> 4;
    int c = hblk & 15;
    #pragma unroll
    for (int i = 0; i < 16; ++i) h[t + 256 * i] = 0;
    __syncthreads();
    int ebase = b * E_ + c * 4096;
    #pragma unroll
    for (int i = 0; i < 16; ++i) {
      int r = rows[ebase + t + 256 * i];
      atomicAdd(&h[r], 1);              // LDS atomic
    }
    __syncthreads();
    int4* hg = reinterpret_cast<int4*>(hist + (size_t)hblk * 4096);
    const int4* hl = reinterpret_cast<const int4*>(h);
    #pragma unroll
    for (int i = 0; i < 4; ++i) hg[t + 256 * i] = hl[t + 256 * i];
  }
}

// per-row exclusive scan over the 16 chunk counts (in-place), emit row totals
__global__ __launch_bounds__(256) void rowscan_kernel(int* __restrict__ hist,
                                                      int* __restrict__ cnt) {
  int rg = blockIdx.x * 256 + threadIdx.x;   // 0..65535 = b*4096+r
  int b = rg >> 12;
  int r = rg & 4095;
  int base = (b * 16) * 4096 + r;
  int h[16];
  #pragma unroll
  for (int c = 0; c < 16; ++c) h[c] = hist[base + c * 4096];
  int run = 0;
  #pragma unroll
  for (int c = 0; c < 16; ++c) {
    int v = h[c];
    hist[base + c * 4096] = run;
    run += v;
  }
  cnt[rg] = run;
}

// scatter edges row-sorted; per-block LDS scan of padded row totals; rank via
// LDS atomics; payload col|bf16(val); chunk-0 blocks publish off[] + pad-fill.
__global__ __launch_bounds__(256) void scatter2_kernel(const int* __restrict__ rows,
                                                       const int* __restrict__ cols,
                                                       const float* __restrict__ vals,
                                                       const int* __restrict__ cnt,
                                                       const int* __restrict__ hist,
                                                       u32* __restrict__ ecv,
                                                       int* __restrict__ off) {
  __shared__ int base[N_];
  __shared__ int cur[N_];
  __shared__ int offl[N_];
  __shared__ int psum[256];
  int xcd = blockIdx.x & 7;
  int j   = blockIdx.x >> 3;              // 0..31
  int b   = xcd * 2 + (j >> 4);
  int c   = j & 15;
  int t   = threadIdx.x;
  // --- in-LDS padded exclusive scan of this batch's row totals ---
  int local[16];
  int s = 0;
  int cbase = b * N_ + t * 16;
  #pragma unroll
  for (int i = 0; i < 16; ++i) {
    local[i] = (cnt[cbase + i] + 3) & ~3;   // pad each row to multiple of 4
    s += local[i];
  }
  psum[t] = s;
  __syncthreads();
  if (t == 0) {
    int run = 0;
    for (int i = 0; i < 256; ++i) { int v = psum[i]; psum[i] = run; run += v; }
  }
  __syncthreads();
  {
    int run = psum[t];
    #pragma unroll
    for (int i = 0; i < 16; ++i) { offl[t * 16 + i] = run; run += local[i]; }
    if (c == 0) {
      #pragma unroll
      for (int i = 0; i < 16; ++i) off[b * (N_ + 1) + t * 16 + i] = offl[t * 16 + i];
      if (t == 255) off[b * (N_ + 1) + N_] = run;
    }
  }
  __syncthreads();
  // --- base = off[row] + chunk prefix; cur = 0 ---
  const int* hb = hist + (b * 16 + c) * 4096;
  #pragma unroll
  for (int i = 0; i < 16; ++i) {
    int idx = t + 256 * i;
    base[idx] = offl[idx] + hb[idx];
    cur[idx] = 0;
  }
  __syncthreads();
  int ebase = b * E_ + c * 4096;
  u32* ecvb = ecv + (size_t)b * ECAP;
  #pragma unroll
  for (int i = 0; i < 16; ++i) {
    int e = ebase + t + 256 * i;
    int r = rows[e];
    int rank = atomicAdd(&cur[r], 1);     // LDS atomic
    u32 pv = (u32)cols[e] | ((u32)f2bf(vals[e]) << 16);
    ecvb[base[r] + rank] = pv;
  }
  if (c == 0) {
    // zero the pad tail of each row (disjoint from all real-edge slots)
    #pragma unroll
    for (int i = 0; i < 16; ++i) {
      int r = t + 256 * i;
      int real = cnt[b * N_ + r];
      int pbase = offl[r] + real;
      int pad = (-real) & 3;
      for (int k = 0; k < pad; ++k) ecvb[pbase + k] = 0;
    }
  }
}

// ---- SpMM pass 1 (bf16 src): g1 = L x; emits bf16 (for GEMM) + fp8 (for pass 2).
// wave = 2 rows x 2 sub-slots x 16 channel-lanes (16B loads, minimal requests).

__global__ __launch_bounds__(256) void spmm_kernel(const u16* __restrict__ src,
                                                   u16* __restrict__ dst,
                                                   u8* __restrict__ dst8,
                                                   const u32* __restrict__ ecv,
                                                   const int* __restrict__ off) {
  int lane = threadIdx.x & 63;
  int wv   = threadIdx.x >> 6;
  int xcd  = blockIdx.x & 7;
  int j    = blockIdx.x >> 3;          // 0..1023
  int b    = xcd * 2 + (j >> 9);
  int rp   = ((j & 511) << 2) | wv;    // row pair 0..2047
  int eg   = lane >> 4;                // slot 0..3
  int cl   = lane & 15;                // channel group (8 bf16 = 16B)
  int n    = rp * 2 + (eg >> 1);       // this lane's row
  int sub  = eg & 1;                   // sub-slot within row
  int s4 = off[b * (N_ + 1) + n] >> 2;
  int e4 = off[b * (N_ + 1) + n + 1] >> 2;
  const uint4* ecv4 = reinterpret_cast<const uint4*>(ecv + (size_t)b * ECAP);
  const u16* srcb = src + (size_t)b * N_ * C_;
  float acc[8];
  #pragma unroll
  for (int t = 0; t < 8; ++t) acc[t] = 0.f;
  for (int gp = s4 + sub; gp < e4; gp += 2) {
    uint4 cv = ecv4[gp];
    u32 e0 = cv.x, e1 = cv.y, e2 = cv.z, e3 = cv.w;
    uint4 u0 = *reinterpret_cast<const uint4*>(srcb + (size_t)(e0 & 0xFFFFu) * C_ + cl * 8);
    uint4 u1 = *reinterpret_cast<const uint4*>(srcb + (size_t)(e1 & 0xFFFFu) * C_ + cl * 8);
    uint4 u2 = *reinterpret_cast<const uint4*>(srcb + (size_t)(e2 & 0xFFFFu) * C_ + cl * 8);
    uint4 u3 = *reinterpret_cast<const uint4*>(srcb + (size_t)(e3 & 0xFFFFu) * C_ + cl * 8);
    float v0 = bfhi(e0), v1 = bfhi(e1), v2 = bfhi(e2), v3 = bfhi(e3);
    acc[0] = fmaf(v0, bflo(u0.x), acc[0]);
    acc[1] = fmaf(v0, bfhi(u0.x), acc[1]);
    acc[2] = fmaf(v0, bflo(u0.y), acc[2]);
    acc[3] = fmaf(v0, bfhi(u0.y), acc[3]);
    acc[4] = fmaf(v0, bflo(u0.z), acc[4]);
    acc[5] = fmaf(v0, bfhi(u0.z), acc[5]);
    acc[6] = fmaf(v0, bflo(u0.w), acc[6]);
    acc[7] = fmaf(v0, bfhi(u0.w), acc[7]);
    acc[0] = fmaf(v1, bflo(u1.x), acc[0]);
    acc[1] = fmaf(v1, bfhi(u1.x), acc[1]);
    acc[2] = fmaf(v1, bflo(u1.y), acc[2]);
    acc[3] = fmaf(v1, bfhi(u1.y), acc[3]);
    acc[4] = fmaf(v1, bflo(u1.z), acc[4]);
    acc[5] = fmaf(v1, bfhi(u1.z), acc[5]);
    acc[6] = fmaf(v1, bflo(u1.w), acc[6]);
    acc[7] = fmaf(v1, bfhi(u1.w), acc[7]);
    acc[0] = fmaf(v2, bflo(u2.x), acc[0]);
    acc[1] = fmaf(v2, bfhi(u2.x), acc[1]);
    acc[2] = fmaf(v2, bflo(u2.y), acc[2]);
    acc[3] = fmaf(v2, bfhi(u2.y), acc[3]);
    acc[4] = fmaf(v2, bflo(u2.z), acc[4]);
    acc[5] = fmaf(v2, bfhi(u2.z), acc[5]);
    acc[6] = fmaf(v2, bflo(u2.w), acc[6]);
    acc[7] = fmaf(v2, bfhi(u2.w), acc[7]);
    acc[0] = fmaf(v3, bflo(u3.x), acc[0]);
    acc[1] = fmaf(v3, bfhi(u3.x), acc[1]);
    acc[2] = fmaf(v3, bflo(u3.y), acc[2]);
    acc[3] = fmaf(v3, bfhi(u3.y), acc[3]);
    acc[4] = fmaf(v3, bflo(u3.z), acc[4]);
    acc[5] = fmaf(v3, bfhi(u3.z), acc[5]);
    acc[6] = fmaf(v3, bflo(u3.w), acc[6]);
    acc[7] = fmaf(v3, bfhi(u3.w), acc[7]);
  }
  #pragma unroll
  for (int t = 0; t < 8; ++t) acc[t] += __shfl_xor(acc[t], 16);
  if (sub == 0) {
    size_t ro = ((size_t)(b * N_ + n)) * C_ + cl * 8;
    uint4 p;
    p.x = (u32)f2bf(acc[0]) | ((u32)f2bf(acc[1]) << 16);
    p.y = (u32)f2bf(acc[2]) | ((u32)f2bf(acc[3]) << 16);
    p.z = (u32)f2bf(acc[4]) | ((u32)f2bf(acc[5]) << 16);
    p.w = (u32)f2bf(acc[6]) | ((u32)f2bf(acc[7]) << 16);
    *reinterpret_cast<uint4*>(dst + ro) = p;
    int q0 = 0, q1 = 0;
    q0 = __builtin_amdgcn_cvt_pk_fp8_f32(acc[0], acc[1], q0, false);
    q0 = __builtin_amdgcn_cvt_pk_fp8_f32(acc[2], acc[3], q0, true);
    q1 = __builtin_amdgcn_cvt_pk_fp8_f32(acc[4], acc[5], q1, false);
    q1 = __builtin_amdgcn_cvt_pk_fp8_f32(acc[6], acc[7], q1, true);
    *reinterpret_cast<uint2*>(dst8 + ro) = make_uint2((u32)q0, (u32)q1);
  }
}

// ---- SpMM passes 2,3 (fp8 e4m3 src -> fp8 dst): request-minimal layout.
// wave = 8 edge-slots x 8 channel-lanes; each lane loads its edge's 16B uint4
// (8 requests/edge vs 16 before). One row per wave; slots 0-3/4-7 take
// alternate uint4 ecv groups; 3-level shfl_xor slot reduction.

__global__ __launch_bounds__(256) void spmm8_kernel(const u8* __restrict__ src8,
                                                    u8* __restrict__ dst8,
                                                    const u32* __restrict__ ecv,
                                                    const int* __restrict__ off) {
  int lane = threadIdx.x & 63;
  int wv   = threadIdx.x >> 6;
  int xcd  = blockIdx.x & 7;
  int j    = blockIdx.x >> 3;          // 0..2047
  int b    = xcd * 2 + (j >> 10);
  int n    = ((j & 1023) << 2) | wv;   // row within batch
  int slot = lane >> 3;                // edge slot 0..7
  int cl   = lane & 7;                 // channel group (16 fp8 = 16B)
  int s4 = off[b * (N_ + 1) + n] >> 2;
  int e4 = off[b * (N_ + 1) + n + 1] >> 2;
  const uint4* ecv4 = reinterpret_cast<const uint4*>(ecv + (size_t)b * ECAP);
  const u8* srcb = src8 + (size_t)b * N_ * C_;
  float acc[16];
  #pragma unroll
  for (int t = 0; t < 16; ++t) acc[t] = 0.f;
  int comp = slot & 3;
  for (int g = s4 + (slot >> 2); g < e4; g += 2) {
    uint4 cv = ecv4[g];                         // broadcast across 32 lanes
    u32 ew = comp == 0 ? cv.x : comp == 1 ? cv.y : comp == 2 ? cv.z : cv.w;
    float v = bfhi(ew);
    uint4 q = *reinterpret_cast<const uint4*>(srcb + (size_t)(ew & 0xFFFFu) * C_ + cl * 16);
    f32x2 p0 = __builtin_amdgcn_cvt_pk_f32_fp8((int)q.x, false);
    f32x2 p1 = __builtin_amdgcn_cvt_pk_f32_fp8((int)q.x, true);
    f32x2 p2 = __builtin_amdgcn_cvt_pk_f32_fp8((int)q.y, false);
    f32x2 p3 = __builtin_amdgcn_cvt_pk_f32_fp8((int)q.y, true);
    f32x2 p4 = __builtin_amdgcn_cvt_pk_f32_fp8((int)q.z, false);
    f32x2 p5 = __builtin_amdgcn_cvt_pk_f32_fp8((int)q.z, true);
    f32x2 p6 = __builtin_amdgcn_cvt_pk_f32_fp8((int)q.w, false);
    f32x2 p7 = __builtin_amdgcn_cvt_pk_f32_fp8((int)q.w, true);
    acc[0]  = fmaf(v, p0.x, acc[0]);
    acc[1]  = fmaf(v, p0.y, acc[1]);
    acc[2]  = fmaf(v, p1.x, acc[2]);
    acc[3]  = fmaf(v, p1.y, acc[3]);
    acc[4]  = fmaf(v, p2.x, acc[4]);
    acc[5]  = fmaf(v, p2.y, acc[5]);
    acc[6]  = fmaf(v, p3.x, acc[6]);
    acc[7]  = fmaf(v, p3.y, acc[7]);
    acc[8]  = fmaf(v, p4.x, acc[8]);
    acc[9]  = fmaf(v, p4.y, acc[9]);
    acc[10] = fmaf(v, p5.x, acc[10]);
    acc[11] = fmaf(v, p5.y, acc[11]);
    acc[12] = fmaf(v, p6.x, acc[12]);
    acc[13] = fmaf(v, p6.y, acc[13]);
    acc[14] = fmaf(v, p7.x, acc[14]);
    acc[15] = fmaf(v, p7.y, acc[15]);
  }
  // reduce the 8 slots (slot bits live in lane bits 3,4,5)
  #pragma unroll
  for (int t = 0; t < 16; ++t) {
    acc[t] += __shfl_xor(acc[t], 8);
    acc[t] += __shfl_xor(acc[t], 16);
    acc[t] += __shfl_xor(acc[t], 32);
  }
  if (slot == 0) {
    size_t ro = ((size_t)(b * N_ + n)) * C_ + cl * 16;
    int q0 = 0, q1 = 0, q2 = 0, q3 = 0;
    q0 = __builtin_amdgcn_cvt_pk_fp8_f32(acc[0],  acc[1],  q0, false);
    q0 = __builtin_amdgcn_cvt_pk_fp8_f32(acc[2],  acc[3],  q0, true);
    q1 = __builtin_amdgcn_cvt_pk_fp8_f32(acc[4],  acc[5],  q1, false);
    q1 = __builtin_amdgcn_cvt_pk_fp8_f32(acc[6],  acc[7],  q1, true);
    q2 = __builtin_amdgcn_cvt_pk_fp8_f32(acc[8],  acc[9],  q2, false);
    q2 = __builtin_amdgcn_cvt_pk_fp8_f32(acc[10], acc[11], q2, true);
    q3 = __builtin_amdgcn_cvt_pk_fp8_f32(acc[12], acc[13], q3, false);
    q3 = __builtin_amdgcn_cvt_pk_fp8_f32(acc[14], acc[15], q3, true);
    *reinterpret_cast<uint4*>(dst8 + ro) = make_uint4((u32)q0, (u32)q1, (u32)q2, (u32)q3);
  }
}

// ---- fused GEMM: out = relu(bias + xb@W0' + g1@W1' + g2@W2' + g3@W3') ----
// 512-thread block (8 waves); wf staged in 128 KiB LDS; wave: 32 rows x 128 cols.
// g2/g3 arrive as fp8 e4m3 and are dequantized in-register to bf16 fragments.

__global__ __launch_bounds__(512) void gemm_kernel(const u16* __restrict__ xb,
                                                   const u16* __restrict__ g1,
                                                   const u8* __restrict__ g2_8,
                                                   const u8* __restrict__ g3_8,
                                                   const u16* __restrict__ wf,
                                                   const float* __restrict__ bias,
                                                   float* __restrict__ out) {
  __shared__ u16 wls[65536];            // 128 KiB: full recombined W (512x128)
  int tid = threadIdx.x;
  #pragma unroll
  for (int i = 0; i < 16; ++i) {
    int chunk = i * 512 + tid;
    reinterpret_cast<uint4*>(wls)[chunk] = reinterpret_cast<const uint4*>(wf)[chunk];
  }
  __syncthreads();
  int lane = tid & 63;
  int w = tid >> 6;                        // wave 0..7
  int xcd = blockIdx.x & 7;
  int j = blockIdx.x >> 3;                 // 0..31
  int b = xcd * 2 + (j >> 4);
  int mb = b * N_ + (j & 15) * 256 + w * 32;
  int g  = lane >> 4;
  int rl = lane & 15;
  f32x4 acc0[8], acc1[8];
  #pragma unroll
  for (int t = 0; t < 8; ++t) {
    acc0[t] = (f32x4){0.f, 0.f, 0.f, 0.f};
    acc1[t] = (f32x4){0.f, 0.f, 0.f, 0.f};
  }
  size_t mrow = (size_t)(mb + rl) * C_;    // element index (bf16 or fp8 alike)
  #pragma unroll
  for (int ks = 0; ks < 16; ++ks) {
    s16x8 a0, a1;
    const int sel = ks >> 2;
    if (sel < 2) {
      const u16* ap = (sel == 0 ? xb : g1) + mrow + (ks & 3) * 32 + g * 8;
      a0 = *reinterpret_cast<const s16x8*>(ap);
      a1 = *reinterpret_cast<const s16x8*>(ap + 16 * C_);
    } else {
      const u8* ap8 = (sel == 2 ? g2_8 : g3_8) + mrow + (ks & 3) * 32 + g * 8;
      uint2 q0 = *reinterpret_cast<const uint2*>(ap8);
      uint2 q1 = *reinterpret_cast<const uint2*>(ap8 + 16 * C_);
      f32x2 p0 = __builtin_amdgcn_cvt_pk_f32_fp8((int)q0.x, false);
      f32x2 p1 = __builtin_amdgcn_cvt_pk_f32_fp8((int)q0.x, true);
      f32x2 p2 = __builtin_amdgcn_cvt_pk_f32_fp8((int)q0.y, false);
      f32x2 p3 = __builtin_amdgcn_cvt_pk_f32_fp8((int)q0.y, true);
      a0[0] = (short)f2bf(p0.x); a0[1] = (short)f2bf(p0.y);
      a0[2] = (short)f2bf(p1.x); a0[3] = (short)f2bf(p1.y);
      a0[4] = (short)f2bf(p2.x); a0[5] = (short)f2bf(p2.y);
      a0[6] = (short)f2bf(p3.x); a0[7] = (short)f2bf(p3.y);
      f32x2 r0 = __builtin_amdgcn_cvt_pk_f32_fp8((int)q1.x, false);
      f32x2 r1 = __builtin_amdgcn_cvt_pk_f32_fp8((int)q1.x, true);
      f32x2 r2 = __builtin_amdgcn_cvt_pk_f32_fp8((int)q1.y, false);
      f32x2 r3 = __builtin_amdgcn_cvt_pk_f32_fp8((int)q1.y, true);
      a1[0] = (short)f2bf(r0.x); a1[1] = (short)f2bf(r0.y);
      a1[2] = (short)f2bf(r1.x); a1[3] = (short)f2bf(r1.y);
      a1[4] = (short)f2bf(r2.x); a1[5] = (short)f2bf(r2.y);
      a1[6] = (short)f2bf(r3.x); a1[7] = (short)f2bf(r3.y);
    }
    const u16* wp = wls + (ks * 8) * 512 + lane * 8;
    #pragma unroll
    for (int ct = 0; ct < 8; ++ct) {
      s16x8 bfv = *reinterpret_cast<const s16x8*>(wp + ct * 512);
      acc0[ct] = __builtin_amdgcn_mfma_f32_16x16x32_bf16(a0, bfv, acc0[ct], 0, 0, 0);
      acc1[ct] = __builtin_amdgcn_mfma_f32_16x16x32_bf16(a1, bfv, acc1[ct], 0, 0, 0);
    }
  }
  #pragma unroll
  for (int ct = 0; ct < 8; ++ct) {
    int o = ct * 16 + rl;
    float bo = bias[o];
    #pragma unroll
    for (int r = 0; r < 4; ++r) {
      int m0 = mb + g * 4 + r;
      int m1 = mb + 16 + g * 4 + r;
      float v0 = acc0[ct][r] + bo;
      float v1 = acc1[ct][r] + bo;
      out[(size_t)m0 * C_ + o] = v0 > 0.f ? v0 : 0.f;
      out[(size_t)m1 * C_ + o] = v1 > 0.f ? v1 : 0.f;
    }
  }
}

// ---- launch --------------------------------------------------------------

extern "C" void kernel_launch(void* const* d_in, const int* in_sizes, int n_in,
                              void* d_out, int out_size, void* d_ws, size_t ws_size,
                              hipStream_t stream) {
  (void)in_sizes; (void)n_in; (void)out_size; (void)ws_size;
  const float* x    = (const float*)d_in[0];
  const float* vals = (const float*)d_in[1];
  const float* wts  = (const float*)d_in[2];
  const float* bias = (const float*)d_in[3];
  const int*   rows = (const int*)d_in[4];
  const int*   cols = (const int*)d_in[5];
  float* out = (float*)d_out;

  const size_t SB = (size_t)B_ * N_ * C_ * sizeof(u16);   // 16.78 MB
  char* ws = (char*)d_ws;
  u16* xb = (u16*)ws;                              // bf16 x
  u16* g1 = (u16*)(ws + SB);                       // bf16 g1 (GEMM operand)
  u8* g2_8 = (u8*)(ws + 2 * SB);                   // fp8 g2 (survives into GEMM)
  u8* g3_8 = (u8*)(ws + 2 * SB + SB / 2);          // fp8 g3 (survives into GEMM)
  char* meta = ws + 4 * SB;
  int* hist = (int*)meta;                          // 16*16*4096*4 = 4 MB
  u32* ecv  = (u32*)(meta + 4194304);              // 16*ECAP*4   = 5.24 MB
  int* cnt  = (int*)(meta + 9437184);              // B*N*4       = 256 KB
  int* off  = (int*)(meta + 9699328);              // B*(N+1)*4   = 262208 B
  u16* wf   = (u16*)(meta + 9961536);              // 128 KB
  // g1 fp8 scratch lives in d_out (dead before gemm writes out)
  u8* g1_8 = (u8*)d_out;                           // 8.39 MB

  prep_kernel<<<4608, 256, 0, stream>>>(x, xb, wts, wf, rows, hist);
  rowscan_kernel<<<256, 256, 0, stream>>>(hist, cnt);
  scatter2_kernel<<<256, 256, 0, stream>>>(rows, cols, vals, cnt, hist, ecv, off);
  // g1 = L x (bf16 gather; emits bf16 + fp8)
  spmm_kernel<<<8192, 256, 0, stream>>>(xb, g1, g1_8, ecv, off);
  // g2 = L g1 (fp8 gather, 8x16B requests/edge; fp8-only output)
  spmm8_kernel<<<16384, 256, 0, stream>>>(g1_8, g2_8, ecv, off);
  // g3 = L g2 (fp8 gather; fp8-only output)
  spmm8_kernel<<<16384, 256, 0, stream>>>(g2_8, g3_8, ecv, off);
  // out = relu(bias + xb@(W0-W2) + g1@(W1-3W3) + g2@(2W2) + g3@(4W3))
  gemm_kernel<<<256, 512, 0, stream>>>(xb, g1, g2_8, g3_8, wf, bias, out);
}

// Round 13
// 110.929 us; speedup vs baseline: 1.3293x; 1.3293x over previous
//
#include <hip/hip_runtime.h>
#include <hip/hip_bf16.h>
#include <stdint.h>

#define B_ 16
#define N_ 4096
#define E_ 65536
#define C_ 128   // CIN == COUT
#define ECAP 81920  // padded edge capacity per batch (E + 3*N = 77824 max)

typedef unsigned short u16;
typedef unsigned int u32;
typedef unsigned char u8;
using f32x4 = __attribute__((ext_vector_type(4))) float;
using f32x2 = __attribute__((ext_vector_type(2))) float;
using s16x8 = __attribute__((ext_vector_type(8))) short;

__device__ __forceinline__ u16 f2bf(float f) {
  u32 u = __builtin_bit_cast(u32, f);
  u = (u + 0x7FFFu + ((u >> 16) & 1u)) >> 16;
  return (u16)u;
}
__device__ __forceinline__ float bflo(u32 u) {   // low bf16 -> f32
  return __builtin_bit_cast(float, u << 16);
}
__device__ __forceinline__ float bfhi(u32 u) {   // high bf16 -> f32
  return __builtin_bit_cast(float, u & 0xFFFF0000u);
}

// ---- prep: fused xconv (blocks 0..4095) + wfrag (4096..4351) + hist (4352..4607)
// wfrag bakes the Chebyshev recombination:
//   out = x(W0-W2) + g1(W1-3W3) + g2(2W2) + g3(4W3),  g_k = L^k x

__global__ __launch_bounds__(256) void prep_kernel(const float* __restrict__ x,
                                                   u16* __restrict__ xb,
                                                   const float* __restrict__ w,
                                                   u16* __restrict__ wf,
                                                   const int* __restrict__ rows,
                                                   int* __restrict__ hist) {
  int blk = blockIdx.x;
  int t = threadIdx.x;
  if (blk < 4096) {
    // x -> bf16, XCD-pinned
    int xcd = blk & 7;
    int j   = blk >> 3;              // 0..511
    int b   = xcd * 2 + (j >> 8);
    size_t base = (size_t)b * N_ * C_ + ((j & 255) * 256 + t) * 8;
    const float4* xp = reinterpret_cast<const float4*>(x + base);
    float4 a0 = xp[0];
    float4 a1 = xp[1];
    uint4 p;
    p.x = (u32)f2bf(a0.x) | ((u32)f2bf(a0.y) << 16);
    p.y = (u32)f2bf(a0.z) | ((u32)f2bf(a0.w) << 16);
    p.z = (u32)f2bf(a1.x) | ((u32)f2bf(a1.y) << 16);
    p.w = (u32)f2bf(a1.z) | ((u32)f2bf(a1.w) << 16);
    *reinterpret_cast<uint4*>(xb + base) = p;
  } else if (blk < 4352) {
    // W fragment pack with recombined weights, MFMA B-operand order
    int tid = (blk - 4096) * 256 + t;   // 0..65535
    int j  = tid & 7;
    int l  = (tid >> 3) & 63;
    int ct = (tid >> 9) & 7;
    int ks = tid >> 12;
    int g  = l >> 4;
    int k  = ks * 32 + g * 8 + j;       // 0..511
    int kk = k >> 7;
    int i  = k & 127;
    int o  = ct * 16 + (l & 15);
    float a = w[(kk * C_ + i) * C_ + o];
    float r;
    if (kk == 0)      r = a - w[(2 * C_ + i) * C_ + o];
    else if (kk == 1) r = a - 3.f * w[(3 * C_ + i) * C_ + o];
    else if (kk == 2) r = 2.f * a;
    else              r = 4.f * a;
    wf[tid] = f2bf(r);
  } else {
    // per-(batch,chunk) LDS histogram of rows
    __shared__ int h[N_];
    int hblk = blk - 4352;              // 0..255
    int b = hblk >> 4;
    int c = hblk & 15;
    #pragma unroll
    for (int i = 0; i < 16; ++i) h[t + 256 * i] = 0;
    __syncthreads();
    int ebase = b * E_ + c * 4096;
    #pragma unroll
    for (int i = 0; i < 16; ++i) {
      int r = rows[ebase + t + 256 * i];
      atomicAdd(&h[r], 1);              // LDS atomic
    }
    __syncthreads();
    int4* hg = reinterpret_cast<int4*>(hist + (size_t)hblk * 4096);
    const int4* hl = reinterpret_cast<const int4*>(h);
    #pragma unroll
    for (int i = 0; i < 4; ++i) hg[t + 256 * i] = hl[t + 256 * i];
  }
}

// per-row exclusive scan over the 16 chunk counts (in-place), emit row totals
__global__ __launch_bounds__(256) void rowscan_kernel(int* __restrict__ hist,
                                                      int* __restrict__ cnt) {
  int rg = blockIdx.x * 256 + threadIdx.x;   // 0..65535 = b*4096+r
  int b = rg >> 12;
  int r = rg & 4095;
  int base = (b * 16) * 4096 + r;
  int h[16];
  #pragma unroll
  for (int c = 0; c < 16; ++c) h[c] = hist[base + c * 4096];
  int run = 0;
  #pragma unroll
  for (int c = 0; c < 16; ++c) {
    int v = h[c];
    hist[base + c * 4096] = run;
    run += v;
  }
  cnt[rg] = run;
}

// scatter edges row-sorted; per-block LDS scan of padded row totals; rank via
// LDS atomics; payload col|bf16(val); chunk-0 blocks publish off[] + pad-fill.
__global__ __launch_bounds__(256) void scatter2_kernel(const int* __restrict__ rows,
                                                       const int* __restrict__ cols,
                                                       const float* __restrict__ vals,
                                                       const int* __restrict__ cnt,
                                                       const int* __restrict__ hist,
                                                       u32* __restrict__ ecv,
                                                       int* __restrict__ off) {
  __shared__ int base[N_];
  __shared__ int cur[N_];
  __shared__ int offl[N_];
  __shared__ int psum[256];
  int xcd = blockIdx.x & 7;
  int j   = blockIdx.x >> 3;              // 0..31
  int b   = xcd * 2 + (j >> 4);
  int c   = j & 15;
  int t   = threadIdx.x;
  // --- in-LDS padded exclusive scan of this batch's row totals ---
  int local[16];
  int s = 0;
  int cbase = b * N_ + t * 16;
  #pragma unroll
  for (int i = 0; i < 16; ++i) {
    local[i] = (cnt[cbase + i] + 3) & ~3;   // pad each row to multiple of 4
    s += local[i];
  }
  psum[t] = s;
  __syncthreads();
  if (t == 0) {
    int run = 0;
    for (int i = 0; i < 256; ++i) { int v = psum[i]; psum[i] = run; run += v; }
  }
  __syncthreads();
  {
    int run = psum[t];
    #pragma unroll
    for (int i = 0; i < 16; ++i) { offl[t * 16 + i] = run; run += local[i]; }
    if (c == 0) {
      #pragma unroll
      for (int i = 0; i < 16; ++i) off[b * (N_ + 1) + t * 16 + i] = offl[t * 16 + i];
      if (t == 255) off[b * (N_ + 1) + N_] = run;
    }
  }
  __syncthreads();
  // --- base = off[row] + chunk prefix; cur = 0 ---
  const int* hb = hist + (b * 16 + c) * 4096;
  #pragma unroll
  for (int i = 0; i < 16; ++i) {
    int idx = t + 256 * i;
    base[idx] = offl[idx] + hb[idx];
    cur[idx] = 0;
  }
  __syncthreads();
  int ebase = b * E_ + c * 4096;
  u32* ecvb = ecv + (size_t)b * ECAP;
  #pragma unroll
  for (int i = 0; i < 16; ++i) {
    int e = ebase + t + 256 * i;
    int r = rows[e];
    int rank = atomicAdd(&cur[r], 1);     // LDS atomic
    u32 pv = (u32)cols[e] | ((u32)f2bf(vals[e]) << 16);
    ecvb[base[r] + rank] = pv;
  }
  if (c == 0) {
    // zero the pad tail of each row (disjoint from all real-edge slots)
    #pragma unroll
    for (int i = 0; i < 16; ++i) {
      int r = t + 256 * i;
      int real = cnt[b * N_ + r];
      int pbase = offl[r] + real;
      int pad = (-real) & 3;
      for (int k = 0; k < pad; ++k) ecvb[pbase + k] = 0;
    }
  }
}

// ---- SpMM pass 1 (bf16 src): g1 = L x; emits bf16 (for GEMM) + fp8 (for pass 2).

__global__ __launch_bounds__(256) void spmm_kernel(const u16* __restrict__ src,
                                                   u16* __restrict__ dst,
                                                   u8* __restrict__ dst8,
                                                   const u32* __restrict__ ecv,
                                                   const int* __restrict__ off) {
  int lane = threadIdx.x & 63;
  int wv   = threadIdx.x >> 6;
  int xcd  = blockIdx.x & 7;
  int j    = blockIdx.x >> 3;          // 0..1023
  int b    = xcd * 2 + (j >> 9);
  int rp   = ((j & 511) << 2) | wv;    // row pair 0..2047
  int eg   = lane >> 4;                // slot 0..3
  int cl   = lane & 15;                // channel group (8 bf16 = 16B)
  int n    = rp * 2 + (eg >> 1);       // this lane's row
  int sub  = eg & 1;                   // sub-slot within row
  int s4 = off[b * (N_ + 1) + n] >> 2;
  int e4 = off[b * (N_ + 1) + n + 1] >> 2;
  const uint4* ecv4 = reinterpret_cast<const uint4*>(ecv + (size_t)b * ECAP);
  const u16* srcb = src + (size_t)b * N_ * C_;
  float acc[8];
  #pragma unroll
  for (int t = 0; t < 8; ++t) acc[t] = 0.f;
  for (int gp = s4 + sub; gp < e4; gp += 2) {
    uint4 cv = ecv4[gp];
    u32 e0 = cv.x, e1 = cv.y, e2 = cv.z, e3 = cv.w;
    uint4 u0 = *reinterpret_cast<const uint4*>(srcb + (size_t)(e0 & 0xFFFFu) * C_ + cl * 8);
    uint4 u1 = *reinterpret_cast<const uint4*>(srcb + (size_t)(e1 & 0xFFFFu) * C_ + cl * 8);
    uint4 u2 = *reinterpret_cast<const uint4*>(srcb + (size_t)(e2 & 0xFFFFu) * C_ + cl * 8);
    uint4 u3 = *reinterpret_cast<const uint4*>(srcb + (size_t)(e3 & 0xFFFFu) * C_ + cl * 8);
    float v0 = bfhi(e0), v1 = bfhi(e1), v2 = bfhi(e2), v3 = bfhi(e3);
    acc[0] = fmaf(v0, bflo(u0.x), acc[0]);
    acc[1] = fmaf(v0, bfhi(u0.x), acc[1]);
    acc[2] = fmaf(v0, bflo(u0.y), acc[2]);
    acc[3] = fmaf(v0, bfhi(u0.y), acc[3]);
    acc[4] = fmaf(v0, bflo(u0.z), acc[4]);
    acc[5] = fmaf(v0, bfhi(u0.z), acc[5]);
    acc[6] = fmaf(v0, bflo(u0.w), acc[6]);
    acc[7] = fmaf(v0, bfhi(u0.w), acc[7]);
    acc[0] = fmaf(v1, bflo(u1.x), acc[0]);
    acc[1] = fmaf(v1, bfhi(u1.x), acc[1]);
    acc[2] = fmaf(v1, bflo(u1.y), acc[2]);
    acc[3] = fmaf(v1, bfhi(u1.y), acc[3]);
    acc[4] = fmaf(v1, bflo(u1.z), acc[4]);
    acc[5] = fmaf(v1, bfhi(u1.z), acc[5]);
    acc[6] = fmaf(v1, bflo(u1.w), acc[6]);
    acc[7] = fmaf(v1, bfhi(u1.w), acc[7]);
    acc[0] = fmaf(v2, bflo(u2.x), acc[0]);
    acc[1] = fmaf(v2, bfhi(u2.x), acc[1]);
    acc[2] = fmaf(v2, bflo(u2.y), acc[2]);
    acc[3] = fmaf(v2, bfhi(u2.y), acc[3]);
    acc[4] = fmaf(v2, bflo(u2.z), acc[4]);
    acc[5] = fmaf(v2, bfhi(u2.z), acc[5]);
    acc[6] = fmaf(v2, bflo(u2.w), acc[6]);
    acc[7] = fmaf(v2, bfhi(u2.w), acc[7]);
    acc[0] = fmaf(v3, bflo(u3.x), acc[0]);
    acc[1] = fmaf(v3, bfhi(u3.x), acc[1]);
    acc[2] = fmaf(v3, bflo(u3.y), acc[2]);
    acc[3] = fmaf(v3, bfhi(u3.y), acc[3]);
    acc[4] = fmaf(v3, bflo(u3.z), acc[4]);
    acc[5] = fmaf(v3, bfhi(u3.z), acc[5]);
    acc[6] = fmaf(v3, bflo(u3.w), acc[6]);
    acc[7] = fmaf(v3, bfhi(u3.w), acc[7]);
  }
  #pragma unroll
  for (int t = 0; t < 8; ++t) acc[t] += __shfl_xor(acc[t], 16);
  if (sub == 0) {
    size_t ro = ((size_t)(b * N_ + n)) * C_ + cl * 8;
    uint4 p;
    p.x = (u32)f2bf(acc[0]) | ((u32)f2bf(acc[1]) << 16);
    p.y = (u32)f2bf(acc[2]) | ((u32)f2bf(acc[3]) << 16);
    p.z = (u32)f2bf(acc[4]) | ((u32)f2bf(acc[5]) << 16);
    p.w = (u32)f2bf(acc[6]) | ((u32)f2bf(acc[7]) << 16);
    *reinterpret_cast<uint4*>(dst + ro) = p;
    int q0 = 0, q1 = 0;
    q0 = __builtin_amdgcn_cvt_pk_fp8_f32(acc[0], acc[1], q0, false);
    q0 = __builtin_amdgcn_cvt_pk_fp8_f32(acc[2], acc[3], q0, true);
    q1 = __builtin_amdgcn_cvt_pk_fp8_f32(acc[4], acc[5], q1, false);
    q1 = __builtin_amdgcn_cvt_pk_fp8_f32(acc[6], acc[7], q1, true);
    *reinterpret_cast<uint2*>(dst8 + ro) = make_uint2((u32)q0, (u32)q1);
  }
}

// ---- SpMM passes 2,3 (fp8 e4m3 src): dst8 = fp8(L src8). fp8-only output:
// GEMM dequants g2/g3 in-register, so the bf16 copy (16.8 MB/pass) is gone.

__global__ __launch_bounds__(256) void spmm8_kernel(const u8* __restrict__ src8,
                                                    u8* __restrict__ dst8,
                                                    const u32* __restrict__ ecv,
                                                    const int* __restrict__ off) {
  int lane = threadIdx.x & 63;
  int wv   = threadIdx.x >> 6;
  int xcd  = blockIdx.x & 7;
  int j    = blockIdx.x >> 3;          // 0..1023
  int b    = xcd * 2 + (j >> 9);
  int rp   = ((j & 511) << 2) | wv;    // row pair 0..2047
  int eg   = lane >> 4;                // slot 0..3
  int cl   = lane & 15;                // channel group (8 fp8 = 8B)
  int n    = rp * 2 + (eg >> 1);
  int sub  = eg & 1;
  int s4 = off[b * (N_ + 1) + n] >> 2;
  int e4 = off[b * (N_ + 1) + n + 1] >> 2;
  const uint4* ecv4 = reinterpret_cast<const uint4*>(ecv + (size_t)b * ECAP);
  const u8* srcb = src8 + (size_t)b * N_ * C_;
  float acc[8];
  #pragma unroll
  for (int t = 0; t < 8; ++t) acc[t] = 0.f;
  for (int gp = s4 + sub; gp < e4; gp += 2) {
    uint4 cv = ecv4[gp];
    u32 e0 = cv.x, e1 = cv.y, e2 = cv.z, e3 = cv.w;
    uint2 q0 = *reinterpret_cast<const uint2*>(srcb + (size_t)(e0 & 0xFFFFu) * C_ + cl * 8);
    uint2 q1 = *reinterpret_cast<const uint2*>(srcb + (size_t)(e1 & 0xFFFFu) * C_ + cl * 8);
    uint2 q2 = *reinterpret_cast<const uint2*>(srcb + (size_t)(e2 & 0xFFFFu) * C_ + cl * 8);
    uint2 q3 = *reinterpret_cast<const uint2*>(srcb + (size_t)(e3 & 0xFFFFu) * C_ + cl * 8);
    float v0 = bfhi(e0), v1 = bfhi(e1), v2 = bfhi(e2), v3 = bfhi(e3);
    {
      f32x2 a = __builtin_amdgcn_cvt_pk_f32_fp8((int)q0.x, false);
      f32x2 c = __builtin_amdgcn_cvt_pk_f32_fp8((int)q0.x, true);
      f32x2 d = __builtin_amdgcn_cvt_pk_f32_fp8((int)q0.y, false);
      f32x2 e = __builtin_amdgcn_cvt_pk_f32_fp8((int)q0.y, true);
      acc[0] = fmaf(v0, a.x, acc[0]);
      acc[1] = fmaf(v0, a.y, acc[1]);
      acc[2] = fmaf(v0, c.x, acc[2]);
      acc[3] = fmaf(v0, c.y, acc[3]);
      acc[4] = fmaf(v0, d.x, acc[4]);
      acc[5] = fmaf(v0, d.y, acc[5]);
      acc[6] = fmaf(v0, e.x, acc[6]);
      acc[7] = fmaf(v0, e.y, acc[7]);
    }
    {
      f32x2 a = __builtin_amdgcn_cvt_pk_f32_fp8((int)q1.x, false);
      f32x2 c = __builtin_amdgcn_cvt_pk_f32_fp8((int)q1.x, true);
      f32x2 d = __builtin_amdgcn_cvt_pk_f32_fp8((int)q1.y, false);
      f32x2 e = __builtin_amdgcn_cvt_pk_f32_fp8((int)q1.y, true);
      acc[0] = fmaf(v1, a.x, acc[0]);
      acc[1] = fmaf(v1, a.y, acc[1]);
      acc[2] = fmaf(v1, c.x, acc[2]);
      acc[3] = fmaf(v1, c.y, acc[3]);
      acc[4] = fmaf(v1, d.x, acc[4]);
      acc[5] = fmaf(v1, d.y, acc[5]);
      acc[6] = fmaf(v1, e.x, acc[6]);
      acc[7] = fmaf(v1, e.y, acc[7]);
    }
    {
      f32x2 a = __builtin_amdgcn_cvt_pk_f32_fp8((int)q2.x, false);
      f32x2 c = __builtin_amdgcn_cvt_pk_f32_fp8((int)q2.x, true);
      f32x2 d = __builtin_amdgcn_cvt_pk_f32_fp8((int)q2.y, false);
      f32x2 e = __builtin_amdgcn_cvt_pk_f32_fp8((int)q2.y, true);
      acc[0] = fmaf(v2, a.x, acc[0]);
      acc[1] = fmaf(v2, a.y, acc[1]);
      acc[2] = fmaf(v2, c.x, acc[2]);
      acc[3] = fmaf(v2, c.y, acc[3]);
      acc[4] = fmaf(v2, d.x, acc[4]);
      acc[5] = fmaf(v2, d.y, acc[5]);
      acc[6] = fmaf(v2, e.x, acc[6]);
      acc[7] = fmaf(v2, e.y, acc[7]);
    }
    {
      f32x2 a = __builtin_amdgcn_cvt_pk_f32_fp8((int)q3.x, false);
      f32x2 c = __builtin_amdgcn_cvt_pk_f32_fp8((int)q3.x, true);
      f32x2 d = __builtin_amdgcn_cvt_pk_f32_fp8((int)q3.y, false);
      f32x2 e = __builtin_amdgcn_cvt_pk_f32_fp8((int)q3.y, true);
      acc[0] = fmaf(v3, a.x, acc[0]);
      acc[1] = fmaf(v3, a.y, acc[1]);
      acc[2] = fmaf(v3, c.x, acc[2]);
      acc[3] = fmaf(v3, c.y, acc[3]);
      acc[4] = fmaf(v3, d.x, acc[4]);
      acc[5] = fmaf(v3, d.y, acc[5]);
      acc[6] = fmaf(v3, e.x, acc[6]);
      acc[7] = fmaf(v3, e.y, acc[7]);
    }
  }
  #pragma unroll
  for (int t = 0; t < 8; ++t) acc[t] += __shfl_xor(acc[t], 16);
  if (sub == 0) {
    size_t ro = ((size_t)(b * N_ + n)) * C_ + cl * 8;
    int q0 = 0, q1 = 0;
    q0 = __builtin_amdgcn_cvt_pk_fp8_f32(acc[0], acc[1], q0, false);
    q0 = __builtin_amdgcn_cvt_pk_fp8_f32(acc[2], acc[3], q0, true);
    q1 = __builtin_amdgcn_cvt_pk_fp8_f32(acc[4], acc[5], q1, false);
    q1 = __builtin_amdgcn_cvt_pk_fp8_f32(acc[6], acc[7], q1, true);
    *reinterpret_cast<uint2*>(dst8 + ro) = make_uint2((u32)q0, (u32)q1);
  }
}

// ---- fused GEMM: out = relu(bias + xb@W0' + g1@W1' + g2@W2' + g3@W3') ----
// 512-thread block (8 waves); wf staged in 128 KiB LDS; wave: 32 rows x 128 cols.
// g2/g3 arrive as fp8 e4m3 and are dequantized in-register to bf16 fragments.

__global__ __launch_bounds__(512) void gemm_kernel(const u16* __restrict__ xb,
                                                   const u16* __restrict__ g1,
                                                   const u8* __restrict__ g2_8,
                                                   const u8* __restrict__ g3_8,
                                                   const u16* __restrict__ wf,
                                                   const float* __restrict__ bias,
                                                   float* __restrict__ out) {
  __shared__ u16 wls[65536];            // 128 KiB: full recombined W (512x128)
  int tid = threadIdx.x;
  #pragma unroll
  for (int i = 0; i < 16; ++i) {
    int chunk = i * 512 + tid;
    reinterpret_cast<uint4*>(wls)[chunk] = reinterpret_cast<const uint4*>(wf)[chunk];
  }
  __syncthreads();
  int lane = tid & 63;
  int w = tid >> 6;                        // wave 0..7
  int xcd = blockIdx.x & 7;
  int j = blockIdx.x >> 3;                 // 0..31
  int b = xcd * 2 + (j >> 4);
  int mb = b * N_ + (j & 15) * 256 + w * 32;
  int g  = lane >> 4;
  int rl = lane & 15;
  f32x4 acc0[8], acc1[8];
  #pragma unroll
  for (int t = 0; t < 8; ++t) {
    acc0[t] = (f32x4){0.f, 0.f, 0.f, 0.f};
    acc1[t] = (f32x4){0.f, 0.f, 0.f, 0.f};
  }
  size_t mrow = (size_t)(mb + rl) * C_;    // element index (bf16 or fp8 alike)
  #pragma unroll
  for (int ks = 0; ks < 16; ++ks) {
    s16x8 a0, a1;
    const int sel = ks >> 2;
    if (sel < 2) {
      const u16* ap = (sel == 0 ? xb : g1) + mrow + (ks & 3) * 32 + g * 8;
      a0 = *reinterpret_cast<const s16x8*>(ap);
      a1 = *reinterpret_cast<const s16x8*>(ap + 16 * C_);
    } else {
      const u8* ap8 = (sel == 2 ? g2_8 : g3_8) + mrow + (ks & 3) * 32 + g * 8;
      uint2 q0 = *reinterpret_cast<const uint2*>(ap8);
      uint2 q1 = *reinterpret_cast<const uint2*>(ap8 + 16 * C_);
      f32x2 p0 = __builtin_amdgcn_cvt_pk_f32_fp8((int)q0.x, false);
      f32x2 p1 = __builtin_amdgcn_cvt_pk_f32_fp8((int)q0.x, true);
      f32x2 p2 = __builtin_amdgcn_cvt_pk_f32_fp8((int)q0.y, false);
      f32x2 p3 = __builtin_amdgcn_cvt_pk_f32_fp8((int)q0.y, true);
      a0[0] = (short)f2bf(p0.x); a0[1] = (short)f2bf(p0.y);
      a0[2] = (short)f2bf(p1.x); a0[3] = (short)f2bf(p1.y);
      a0[4] = (short)f2bf(p2.x); a0[5] = (short)f2bf(p2.y);
      a0[6] = (short)f2bf(p3.x); a0[7] = (short)f2bf(p3.y);
      f32x2 r0 = __builtin_amdgcn_cvt_pk_f32_fp8((int)q1.x, false);
      f32x2 r1 = __builtin_amdgcn_cvt_pk_f32_fp8((int)q1.x, true);
      f32x2 r2 = __builtin_amdgcn_cvt_pk_f32_fp8((int)q1.y, false);
      f32x2 r3 = __builtin_amdgcn_cvt_pk_f32_fp8((int)q1.y, true);
      a1[0] = (short)f2bf(r0.x); a1[1] = (short)f2bf(r0.y);
      a1[2] = (short)f2bf(r1.x); a1[3] = (short)f2bf(r1.y);
      a1[4] = (short)f2bf(r2.x); a1[5] = (short)f2bf(r2.y);
      a1[6] = (short)f2bf(r3.x); a1[7] = (short)f2bf(r3.y);
    }
    const u16* wp = wls + (ks * 8) * 512 + lane * 8;
    #pragma unroll
    for (int ct = 0; ct < 8; ++ct) {
      s16x8 bfv = *reinterpret_cast<const s16x8*>(wp + ct * 512);
      acc0[ct] = __builtin_amdgcn_mfma_f32_16x16x32_bf16(a0, bfv, acc0[ct], 0, 0, 0);
      acc1[ct] = __builtin_amdgcn_mfma_f32_16x16x32_bf16(a1, bfv, acc1[ct], 0, 0, 0);
    }
  }
  #pragma unroll
  for (int ct = 0; ct < 8; ++ct) {
    int o = ct * 16 + rl;
    float bo = bias[o];
    #pragma unroll
    for (int r = 0; r < 4; ++r) {
      int m0 = mb + g * 4 + r;
      int m1 = mb + 16 + g * 4 + r;
      float v0 = acc0[ct][r] + bo;
      float v1 = acc1[ct][r] + bo;
      out[(size_t)m0 * C_ + o] = v0 > 0.f ? v0 : 0.f;
      out[(size_t)m1 * C_ + o] = v1 > 0.f ? v1 : 0.f;
    }
  }
}

// ---- launch --------------------------------------------------------------

extern "C" void kernel_launch(void* const* d_in, const int* in_sizes, int n_in,
                              void* d_out, int out_size, void* d_ws, size_t ws_size,
                              hipStream_t stream) {
  (void)in_sizes; (void)n_in; (void)out_size; (void)ws_size;
  const float* x    = (const float*)d_in[0];
  const float* vals = (const float*)d_in[1];
  const float* wts  = (const float*)d_in[2];
  const float* bias = (const float*)d_in[3];
  const int*   rows = (const int*)d_in[4];
  const int*   cols = (const int*)d_in[5];
  float* out = (float*)d_out;

  const size_t SB = (size_t)B_ * N_ * C_ * sizeof(u16);   // 16.78 MB
  char* ws = (char*)d_ws;
  u16* xb = (u16*)ws;                              // bf16 x
  u16* g1 = (u16*)(ws + SB);                       // bf16 g1 (GEMM operand)
  u8* g2_8 = (u8*)(ws + 2 * SB);                   // fp8 g2 (survives into GEMM)
  u8* g3_8 = (u8*)(ws + 2 * SB + SB / 2);          // fp8 g3 (survives into GEMM)
  char* meta = ws + 4 * SB;
  int* hist = (int*)meta;                          // 16*16*4096*4 = 4 MB
  u32* ecv  = (u32*)(meta + 4194304);              // 16*ECAP*4   = 5.24 MB
  int* cnt  = (int*)(meta + 9437184);              // B*N*4       = 256 KB
  int* off  = (int*)(meta + 9699328);              // B*(N+1)*4   = 262208 B
  u16* wf   = (u16*)(meta + 9961536);              // 128 KB
  // g1 fp8 scratch lives in d_out (dead before gemm writes out)
  u8* g1_8 = (u8*)d_out;                           // 8.39 MB

  prep_kernel<<<4608, 256, 0, stream>>>(x, xb, wts, wf, rows, hist);
  rowscan_kernel<<<256, 256, 0, stream>>>(hist, cnt);
  scatter2_kernel<<<256, 256, 0, stream>>>(rows, cols, vals, cnt, hist, ecv, off);
  // g1 = L x (bf16 gather; emits bf16 + fp8)
  spmm_kernel<<<8192, 256, 0, stream>>>(xb, g1, g1_8, ecv, off);
  // g2 = L g1 (fp8 gather; fp8-only output)
  spmm8_kernel<<<8192, 256, 0, stream>>>(g1_8, g2_8, ecv, off);
  // g3 = L g2 (fp8 gather; fp8-only output)
  spmm8_kernel<<<8192, 256, 0, stream>>>(g2_8, g3_8, ecv, off);
  // out = relu(bias + xb@(W0-W2) + g1@(W1-3W3) + g2@(2W2) + g3@(4W3))
  gemm_kernel<<<256, 512, 0, stream>>>(xb, g1, g2_8, g3_8, wf, bias, out);
}